// Round 7
// baseline (351.302 us; speedup 1.0000x reference)
//
#include <hip/hip_runtime.h>

#define NN 100000
#define NE 1600000
#define DF 128
#define DOUT 64
#define NG 128
#define NB 391      // ceil(NN/256) buckets of 256 nodes
#define EPB 2048    // edges per block in binning passes (no global atomics -> small is safe)
#define NBLKA ((NE + EPB - 1) / EPB)  // 782
#define PCH 8       // pool chunks per graph
#define NAGB (NN / 16)  // agg blocks: 16 nodes per block (4 waves x 4 nodes)

typedef short short8 __attribute__((ext_vector_type(8)));
typedef float floatx4 __attribute__((ext_vector_type(4)));
typedef float floatx2 __attribute__((ext_vector_type(2)));

__device__ __forceinline__ unsigned short f2bf(float f) {
    unsigned int b = __float_as_uint(f);
    unsigned int r = (b + 0x7fffu + ((b >> 16) & 1u)) >> 16;
    return (unsigned short)r;
}
__device__ __forceinline__ float bf2f_lo(unsigned int v) { return __uint_as_float(v << 16); }
__device__ __forceinline__ float bf2f_hi(unsigned int v) { return __uint_as_float(v & 0xffff0000u); }

// physical feature index p -> logical feature c.
__device__ __forceinline__ int phi(int p) {
    return (((p >> 6) << 2) + (p & 3)) * 16 + ((p >> 2) & 15);
}

// ---------------- fused init: dst histogram + graph bounds + prepw ----------------

__global__ __launch_bounds__(256) void k_init(const int* __restrict__ dst,
                                              int* __restrict__ hist,
                                              const int* __restrict__ batch,
                                              int* __restrict__ gstart,
                                              int* __restrict__ ticket,
                                              int* __restrict__ col,
                                              const float* __restrict__ b1,
                                              const float* __restrict__ b2,
                                              const float* __restrict__ b3,
                                              float* __restrict__ bp,
                                              const float* __restrict__ W1,
                                              const float* __restrict__ W2,
                                              const float* __restrict__ W3,
                                              unsigned short* __restrict__ O1,
                                              unsigned short* __restrict__ O2,
                                              unsigned short* __restrict__ O3) {
    __shared__ int lh[NB];
    int blk = blockIdx.x;
    int t = threadIdx.x;
    if (blk < NBLKA) {
        for (int i = t; i < NB; i += 256) lh[i] = 0;
        __syncthreads();
        int e0 = blk * EPB;
        int e1 = min(e0 + EPB, NE);
        for (int e = e0 + t; e < e1; e += 256) atomicAdd(&lh[dst[e] >> 8], 1);
        __syncthreads();
        for (int i = t; i < NB; i += 256) hist[blk * NB + i] = lh[i];
    } else if (blk == NBLKA) {
        int g = t;
        if (g > NG) return;
        int lo = 0, hi = NN;
        while (lo < hi) {
            int mid = (lo + hi) >> 1;
            if (batch[mid] < g) lo = mid + 1; else hi = mid;
        }
        gstart[g] = lo;
    } else if (blk == NBLKA + 1) {
        if (t == 0) *ticket = 0;
        if (t >= 8 && t < 16) col[NE + (t - 8)] = 0;  // pad: unclamped tail reads
        if (t < 128) {
            int c = phi(t);
            bp[t] = b1[c];
            bp[128 + t] = b2[c];
            bp[256 + t] = b3[c];
        }
    } else {
        int bb = blk - (NBLKA + 2);
        const float* W = (bb >= 16) ? W3 : (bb >= 8) ? W2 : W1;
        unsigned short* O = (bb >= 16) ? O3 : (bb >= 8) ? O2 : O1;
        bool logical = (bb < 8);
        int idx = (bb & 7) * 256 + t;
        int l = idx & 63;
        int s = (idx >> 6) & 3;
        int tt = idx >> 8;
        int k0 = s * 32 + (l >> 4) * 8;
        int c = tt * 16 + (l & 15);
        unsigned short o[8];
#pragma unroll
        for (int j = 0; j < 8; j++) {
            int kk = logical ? (k0 + j) : phi(k0 + j);
            o[j] = f2bf(W[kk * DF + c]);
        }
        *(short8*)&O[idx * 8] = *(short8*)o;
    }
}

// ---------------- merged hscan + bscan (last-block ticket); 2 chunks/thread ----------------

__global__ __launch_bounds__(512) void k_scan(int* __restrict__ hist,
                                              int* __restrict__ bhist,
                                              int* __restrict__ bbase,
                                              int* __restrict__ ticket) {
    __shared__ int sh[512];
    __shared__ int amLast;
    int b = blockIdx.x, t = threadIdx.x;
    int c0 = 2 * t, c1 = 2 * t + 1;
    int v0 = (c0 < NBLKA) ? hist[c0 * NB + b] : 0;
    int v1 = (c1 < NBLKA) ? hist[c1 * NB + b] : 0;
    sh[t] = v0 + v1;
    __syncthreads();
    for (int off = 1; off < 512; off <<= 1) {
        int a = (t >= off) ? sh[t - off] : 0;
        __syncthreads();
        sh[t] += a;
        __syncthreads();
    }
    int excl = sh[t] - (v0 + v1);
    if (c0 < NBLKA) hist[c0 * NB + b] = excl;
    if (c1 < NBLKA) hist[c1 * NB + b] = excl + v0;
    if (t == 511) atomicExch(&bhist[b], sh[511]);
    __syncthreads();
    if (t == 0) {
        __threadfence();
        amLast = (atomicAdd(ticket, 1) == NB - 1) ? 1 : 0;
    }
    __syncthreads();
    if (amLast) {
        int v2 = (t < NB) ? atomicAdd(&bhist[t], 0) : 0;
        __syncthreads();
        sh[t] = v2;
        __syncthreads();
        for (int off = 1; off < 512; off <<= 1) {
            int a = (t >= off) ? sh[t - off] : 0;
            __syncthreads();
            sh[t] += a;
            __syncthreads();
        }
        if (t < NB) bbase[t] = sh[t] - v2;
        if (t == NB - 1) bbase[NB] = sh[t];
    }
}

// scatter only. ebuf packed: (src << 8) | (dst & 255)
__global__ __launch_bounds__(256) void k_pairs(const int* __restrict__ src,
                                               const int* __restrict__ dst,
                                               const int* __restrict__ hist,
                                               const int* __restrict__ bbase,
                                               int* __restrict__ ebuf) {
    __shared__ int lh[NB];
    __shared__ int lbase[NB];
    int t = threadIdx.x;
    for (int i = t; i < NB; i += 256) {
        lh[i] = 0;
        lbase[i] = bbase[i] + hist[blockIdx.x * NB + i];
    }
    __syncthreads();
    int e0 = blockIdx.x * EPB;
    int e1 = min(e0 + EPB, NE);
    for (int e = e0 + t; e < e1; e += 256) {
        int s = src[e], d = dst[e];
        int bk = d >> 8;
        int off = atomicAdd(&lh[bk], 1);
        ebuf[lbase[bk] + off] = (s << 8) | (d & 255);
    }
}

// CSR build + degree info for the degree-sorted permutation
__global__ __launch_bounds__(256) void k_build(const int* __restrict__ ebuf,
                                               const int* __restrict__ bbase,
                                               int* __restrict__ rowptr,
                                               float* __restrict__ dinv,
                                               int* __restrict__ col,
                                               unsigned char* __restrict__ deg8,
                                               int* __restrict__ dh) {
    __shared__ int deg[256];
    __shared__ int lst[256];
    __shared__ int dbin[64];
    int b = blockIdx.x, t = threadIdx.x;
    int node = (b << 8) + t;
    deg[t] = 0;
    if (t < 64) dbin[t] = 0;
    __syncthreads();
    int e0 = bbase[b], e1 = bbase[b + 1];
    for (int e = e0 + t; e < e1; e += 256) atomicAdd(&deg[ebuf[e] & 255], 1);
    __syncthreads();
    int v = deg[t];
    lst[t] = v;
    __syncthreads();
    for (int off = 1; off < 256; off <<= 1) {
        int a = (t >= off) ? lst[t - off] : 0;
        __syncthreads();
        lst[t] += a;
        __syncthreads();
    }
    int mystart = e0 + lst[t] - v;
    int d8 = min(v, 63);
    if (node < NN) {
        rowptr[node] = mystart;
        dinv[node] = rsqrtf((float)(v + 1));  // +1 self-loop
        deg8[node] = (unsigned char)d8;
        atomicAdd(&dbin[d8], 1);
    }
    if (b == NB - 1 && t == 255) rowptr[NN] = e1;
    lst[t] = mystart;
    __syncthreads();
    for (int e = e0 + t; e < e1; e += 256) {
        int pk = ebuf[e];
        int p = atomicAdd(&lst[pk & 255], 1);
        col[p] = (pk >> 8) * DF;
    }
    __syncthreads();
    if (t < 64) dh[b * 64 + t] = dbin[t];
}

// per-bin exclusive scan over the NB build-blocks; bin totals -> dtot
__global__ __launch_bounds__(512) void k_dscan(int* __restrict__ dh,
                                               int* __restrict__ dtot) {
    __shared__ int sh[512];
    int bin = blockIdx.x, t = threadIdx.x;
    int v = (t < NB) ? dh[t * 64 + bin] : 0;
    sh[t] = v;
    __syncthreads();
    for (int off = 1; off < 512; off <<= 1) {
        int a = (t >= off) ? sh[t - off] : 0;
        __syncthreads();
        sh[t] += a;
        __syncthreads();
    }
    if (t < NB) dh[t * 64 + bin] = sh[t] - v;
    if (t == 511) dtot[bin] = sh[511];
}

// emit degree-sorted permutation: slot = dbase[bin] + dh_ex[blk][bin] + local
__global__ __launch_bounds__(256) void k_dperm(const unsigned char* __restrict__ deg8,
                                               const int* __restrict__ dh,
                                               const int* __restrict__ dtot,
                                               int* __restrict__ perm) {
    __shared__ int dbase[64];
    __shared__ int dcnt[64];
    int b = blockIdx.x, t = threadIdx.x;
    if (t < 64) dbase[t] = dtot[t];
    __syncthreads();
    for (int off = 1; off < 64; off <<= 1) {
        int a = (t >= off && t < 64) ? dbase[t - off] : 0;
        __syncthreads();
        if (t < 64) dbase[t] += a;
        __syncthreads();
    }
    if (t < 64) {
        dbase[t] -= dtot[t];  // exclusive
        dcnt[t] = 0;
    }
    __syncthreads();
    int node = b * 256 + t;
    if (node < NN) {
        int d8 = deg8[node];
        int off = atomicAdd(&dcnt[d8], 1);
        perm[dbase[d8] + dh[b * 64 + d8] + off] = node;
    }
}

// ---------------- per-layer compute ----------------

__device__ __forceinline__ void gemm_core(const short8* af,
                                          const unsigned short* __restrict__ Wb,
                                          const float* __restrict__ dinv,
                                          int lane, int lm, int orow,
                                          unsigned char* __restrict__ fs8) {
    float dv[4];
#pragma unroll
    for (int j = 0; j < 4; j++) dv[j] = (orow + j < NN) ? dinv[orow + j] : 0.f;

    float res[4][8];
#pragma unroll
    for (int tt = 0; tt < 8; tt++) {
        floatx4 acc = {0.f, 0.f, 0.f, 0.f};
        const unsigned short* wp = Wb + ((size_t)(tt * 4) * 64 + lane) * 8;
        acc = __builtin_amdgcn_mfma_f32_16x16x32_bf16(af[0], *(const short8*)(wp), acc, 0, 0, 0);
        acc = __builtin_amdgcn_mfma_f32_16x16x32_bf16(af[1], *(const short8*)(wp + 512), acc, 0, 0, 0);
        acc = __builtin_amdgcn_mfma_f32_16x16x32_bf16(af[2], *(const short8*)(wp + 1024), acc, 0, 0, 0);
        acc = __builtin_amdgcn_mfma_f32_16x16x32_bf16(af[3], *(const short8*)(wp + 1536), acc, 0, 0, 0);
#pragma unroll
        for (int j = 0; j < 4; j++) res[j][tt] = acc[j] * dv[j];
    }

#pragma unroll
    for (int g = 0; g < 2; g++) {
#pragma unroll
        for (int j = 0; j < 4; j++) {
            int r = orow + j;
            if (r >= NN) continue;
            unsigned int w8 = __builtin_amdgcn_cvt_pk_fp8_f32(res[j][g * 4 + 0], res[j][g * 4 + 1], 0, false);
            w8 = __builtin_amdgcn_cvt_pk_fp8_f32(res[j][g * 4 + 2], res[j][g * 4 + 3], w8, true);
            *(unsigned int*)&fs8[(size_t)r * DF + g * 64 + lm * 4] = w8;
        }
    }
}

__global__ __launch_bounds__(256) void k_gemm1(const float* __restrict__ X,
                                               const unsigned short* __restrict__ Wb,
                                               const float* __restrict__ dinv,
                                               unsigned char* __restrict__ fs8) {
    int t = threadIdx.x;
    int wave = t >> 6, l = t & 63;
    int r0 = blockIdx.x * 64 + wave * 16;
    int lm = l & 15, q = l >> 4;

    int arow = r0 + lm;
    if (arow >= NN) arow = NN - 1;
    const float* xrow = X + (size_t)arow * DF + q * 8;
    short8 af[4];
#pragma unroll
    for (int s = 0; s < 4; s++) {
        float4 f0 = *(const float4*)(xrow + s * 32);
        float4 f1 = *(const float4*)(xrow + s * 32 + 4);
        unsigned short o[8] = {f2bf(f0.x), f2bf(f0.y), f2bf(f0.z), f2bf(f0.w),
                               f2bf(f1.x), f2bf(f1.y), f2bf(f1.z), f2bf(f1.w)};
        af[s] = *(short8*)o;
    }
    gemm_core(af, Wb, dinv, l, lm, r0 + q * 4, fs8);
}

__global__ __launch_bounds__(256) void k_gemm(const unsigned short* __restrict__ X,
                                              const unsigned short* __restrict__ Wb,
                                              const float* __restrict__ dinv,
                                              unsigned char* __restrict__ fs8) {
    int t = threadIdx.x;
    int wave = t >> 6, l = t & 63;
    int r0 = blockIdx.x * 64 + wave * 16;
    int lm = l & 15, q = l >> 4;

    int arow = r0 + lm;
    if (arow >= NN) arow = NN - 1;
    const unsigned short* xrow = X + (size_t)arow * DF + q * 8;
    short8 af[4];
#pragma unroll
    for (int s = 0; s < 4; s++) af[s] = *(const short8*)(xrow + s * 32);
    gemm_core(af, Wb, dinv, l, lm, r0 + q * 4, fs8);
}

// aggregation core (unchanged round-5/6 shape: 8-deep, unclamped col, predicated)
__device__ __forceinline__ void agg_node(const unsigned char* __restrict__ fsl, // fs8 + foff
                                         const int* __restrict__ colb,
                                         size_t selfoff, int e0, int e1,
                                         float dvn, const float* bias,
                                         float* o) {
    floatx2 acc0 = {0.f, 0.f}, acc1 = {0.f, 0.f}, acc2 = {0.f, 0.f}, acc3 = {0.f, 0.f};
    for (int base = e0; base < e1; base += 8) {
        const int* cp = colb + base;
        int cb[8];
#pragma unroll
        for (int k = 0; k < 8; k++) cb[k] = cp[k];
        uint2 vv[8];
#pragma unroll
        for (int k = 0; k < 8; k++) vv[k] = *(const uint2*)(fsl + cb[k]);
#pragma unroll
        for (int k = 0; k < 8; k++) {
            if (base + k < e1) {
                acc0 += __builtin_amdgcn_cvt_pk_f32_fp8(vv[k].x, false);
                acc1 += __builtin_amdgcn_cvt_pk_f32_fp8(vv[k].x, true);
                acc2 += __builtin_amdgcn_cvt_pk_f32_fp8(vv[k].y, false);
                acc3 += __builtin_amdgcn_cvt_pk_f32_fp8(vv[k].y, true);
            }
        }
    }
    uint2 sv = *(const uint2*)(fsl + selfoff);
    acc0 += __builtin_amdgcn_cvt_pk_f32_fp8(sv.x, false);
    acc1 += __builtin_amdgcn_cvt_pk_f32_fp8(sv.x, true);
    acc2 += __builtin_amdgcn_cvt_pk_f32_fp8(sv.y, false);
    acc3 += __builtin_amdgcn_cvt_pk_f32_fp8(sv.y, true);

    float a[8] = {acc0.x, acc0.y, acc1.x, acc1.y, acc2.x, acc2.y, acc3.x, acc3.y};
#pragma unroll
    for (int j = 0; j < 8; j++) o[j] = fmaxf(dvn * a[j] + bias[j], 0.f);
}

// 4 nodes per wave via degree-sorted perm: subs in a wave get equal-degree
// nodes -> no gather-loop divergence. Per-node math order unchanged.
__global__ __launch_bounds__(256) void k_agg(const unsigned char* __restrict__ fs8,
                                             const int* __restrict__ colb,
                                             const int* __restrict__ rowptr,
                                             const float* __restrict__ dinv,
                                             const float* __restrict__ bp,
                                             const int* __restrict__ perm,
                                             unsigned short* __restrict__ out) {
    int w = (int)((blockIdx.x * (size_t)blockDim.x + threadIdx.x) >> 6);
    int lane = threadIdx.x & 63;
    int sub = lane >> 4;
    int fo = lane & 15;
    int foff = fo * 8;
    int n = perm[w * 4 + sub];

    float4 bA = *(const float4*)&bp[foff];
    float4 bB = *(const float4*)&bp[foff + 4];
    float bias[8] = {bA.x, bA.y, bA.z, bA.w, bB.x, bB.y, bB.z, bB.w};
    float dvn = dinv[n];
    int e0 = rowptr[n], e1 = rowptr[n + 1];

    float o[8];
    agg_node(fs8 + foff, colb, (size_t)n * DF, e0, e1, dvn, bias, o);

    uint4 pk;
    pk.x = (unsigned int)f2bf(o[0]) | ((unsigned int)f2bf(o[1]) << 16);
    pk.y = (unsigned int)f2bf(o[2]) | ((unsigned int)f2bf(o[3]) << 16);
    pk.z = (unsigned int)f2bf(o[4]) | ((unsigned int)f2bf(o[5]) << 16);
    pk.w = (unsigned int)f2bf(o[6]) | ((unsigned int)f2bf(o[7]) << 16);
    *(uint4*)&out[(size_t)n * DF + foff] = pk;
}

// ---------------- pooling + FC ----------------

__global__ __launch_bounds__(256) void k_poolA(const unsigned short* __restrict__ h,
                                               const int* __restrict__ gstart,
                                               float* __restrict__ part) {
    __shared__ float2 red[256];
    int g = blockIdx.x >> 3, c = blockIdx.x & 7;
    int s = gstart[g], e = gstart[g + 1];
    int len = e - s;
    int cs = s + (int)(((long long)len * c) >> 3);
    int ce = s + (int)(((long long)len * (c + 1)) >> 3);
    int t = threadIdx.x;
    int fp = t & 63;
    int rs = t >> 6;
    float2 acc = make_float2(0.f, 0.f);
    for (int n = cs + rs; n < ce; n += 4) {
        unsigned int v = *(const unsigned int*)&h[(size_t)n * DF + fp * 2];
        acc.x += bf2f_lo(v);
        acc.y += bf2f_hi(v);
    }
    red[t] = acc;
    __syncthreads();
    if (rs == 0) {
        float2 a0 = red[fp], a1 = red[fp + 64], a2 = red[fp + 128], a3 = red[fp + 192];
        float2 o;
        o.x = (a0.x + a1.x) + (a2.x + a3.x);
        o.y = (a0.y + a1.y) + (a2.y + a3.y);
        *(float2*)&part[(size_t)blockIdx.x * DF + fp * 2] = o;
    }
}

__global__ __launch_bounds__(128) void k_poolfc(const float* __restrict__ part,
                                                const int* __restrict__ gstart,
                                                const float* __restrict__ Wfc,
                                                const float* __restrict__ bfc,
                                                float* __restrict__ out) {
    __shared__ float pl[DF];
    int g = blockIdx.x;
    int f = threadIdx.x;
    float s = 0.f;
#pragma unroll
    for (int c = 0; c < PCH; c++) s += part[(size_t)(g * PCH + c) * DF + f];
    int cnt = gstart[g + 1] - gstart[g];
    pl[phi(f)] = s / (float)max(cnt, 1);
    __syncthreads();
    if (f < DOUT) {
        float acc = bfc[f];
        for (int k = 0; k < DF; k++) acc += pl[k] * Wfc[k * DOUT + f];
        out[g * DOUT + f] = acc;
    }
}

// ---------------- launch ----------------

extern "C" void kernel_launch(void* const* d_in, const int* in_sizes, int n_in,
                              void* d_out, int out_size, void* d_ws, size_t ws_size,
                              hipStream_t stream) {
    const float* x     = (const float*)d_in[0];
    const int*   ei    = (const int*)d_in[1];
    const int*   batch = (const int*)d_in[2];
    const float* W1 = (const float*)d_in[3];
    const float* b1 = (const float*)d_in[4];
    const float* W2 = (const float*)d_in[5];
    const float* b2 = (const float*)d_in[6];
    const float* W3 = (const float*)d_in[7];
    const float* b3 = (const float*)d_in[8];
    const float* Wfc = (const float*)d_in[9];
    const float* bfc = (const float*)d_in[10];
    float* out = (float*)d_out;

    char* p = (char*)d_ws;
    unsigned short* ob = (unsigned short*)p;  p += (size_t)NN * DF * sizeof(short);
    unsigned char*  fs8 = (unsigned char*)p;  p += (size_t)NN * DF + 256;
    unsigned short* Wb1 = (unsigned short*)p; p += 16384 * sizeof(short);
    unsigned short* Wb2 = (unsigned short*)p; p += 16384 * sizeof(short);
    unsigned short* Wb3 = (unsigned short*)p; p += 16384 * sizeof(short);
    float* dinv = (float*)p;           p += (size_t)NN * sizeof(float);
    int* rowptr = (int*)p;             p += (size_t)(NN + 4) * sizeof(int);
    int* col    = (int*)p;             p += (size_t)(NE + 8) * sizeof(int);
    int* ebuf   = (int*)p;             p += (size_t)NE * sizeof(int);
    int* bhist  = (int*)p;             p += (size_t)(NB + 4) * sizeof(int);
    int* bbase  = (int*)p;             p += (size_t)(NB + 4) * sizeof(int);
    int* hist   = (int*)p;             p += (size_t)NBLKA * NB * sizeof(int);
    int* gstart = (int*)p;             p += (size_t)(NG + 4) * sizeof(int);
    int* ticket = (int*)p;             p += 4 * sizeof(int);
    float* bp   = (float*)p;           p += 384 * sizeof(float);
    unsigned char* deg8 = (unsigned char*)p; p += (size_t)(NN + 64);
    int* dh     = (int*)p;             p += (size_t)NB * 64 * sizeof(int);
    int* dtot   = (int*)p;             p += 64 * sizeof(int);
    int* perm   = (int*)p;             p += (size_t)NN * sizeof(int);
    float* part = (float*)p;           p += (size_t)NG * PCH * DF * sizeof(float);

    const int* e_src = ei;
    const int* e_dst = ei + NE;

    // binning + CSR + degree-sorted permutation
    k_init<<<NBLKA + 26, 256, 0, stream>>>(e_dst, hist, batch, gstart, ticket, col,
                                           b1, b2, b3, bp,
                                           W1, W2, W3, Wb1, Wb2, Wb3);
    k_scan<<<NB, 512, 0, stream>>>(hist, bhist, bbase, ticket);
    k_pairs<<<NBLKA, 256, 0, stream>>>(e_src, e_dst, hist, bbase, ebuf);
    k_build<<<NB, 256, 0, stream>>>(ebuf, bbase, rowptr, dinv, col, deg8, dh);
    k_dscan<<<64, 512, 0, stream>>>(dh, dtot);
    k_dperm<<<NB, 256, 0, stream>>>(deg8, dh, dtot, perm);

    int ggrid = (NN + 63) / 64;

    // layer 1 (direct f32 x), layers 2-3 (bf16 activations)
    k_gemm1<<<ggrid, 256, 0, stream>>>(x, Wb1, dinv, fs8);
    k_agg<<<NAGB, 256, 0, stream>>>(fs8, col, rowptr, dinv, bp, perm, ob);
    k_gemm<<<ggrid, 256, 0, stream>>>(ob, Wb2, dinv, fs8);
    k_agg<<<NAGB, 256, 0, stream>>>(fs8, col, rowptr, dinv, bp + 128, perm, ob);
    k_gemm<<<ggrid, 256, 0, stream>>>(ob, Wb3, dinv, fs8);
    k_agg<<<NAGB, 256, 0, stream>>>(fs8, col, rowptr, dinv, bp + 256, perm, ob);

    // pool + fc
    k_poolA<<<NG * PCH, 256, 0, stream>>>(ob, gstart, part);
    k_poolfc<<<NG, 128, 0, stream>>>(part, gstart, Wfc, bfc, out);
}

// Round 8
// 343.253 us; speedup vs baseline: 1.0234x; 1.0234x over previous
//
#include <hip/hip_runtime.h>

#define NN 100000
#define NE 1600000
#define DF 128
#define DOUT 64
#define NG 128
#define NB 391      // ceil(NN/256) buckets of 256 nodes
#define EPB 8192    // edges per block in binning passes
#define NBLKA ((NE + EPB - 1) / EPB)  // 196
#define PCH 8       // pool chunks per graph
#define NAGB (NN / 16)  // agg blocks: 16 nodes per block (4 waves x 4 nodes)

typedef short short8 __attribute__((ext_vector_type(8)));
typedef float floatx4 __attribute__((ext_vector_type(4)));
typedef float floatx2 __attribute__((ext_vector_type(2)));

__device__ __forceinline__ unsigned short f2bf(float f) {
    unsigned int b = __float_as_uint(f);
    unsigned int r = (b + 0x7fffu + ((b >> 16) & 1u)) >> 16;
    return (unsigned short)r;
}
__device__ __forceinline__ float bf2f_lo(unsigned int v) { return __uint_as_float(v << 16); }
__device__ __forceinline__ float bf2f_hi(unsigned int v) { return __uint_as_float(v & 0xffff0000u); }

// physical feature index p -> logical feature c.
__device__ __forceinline__ int phi(int p) {
    return (((p >> 6) << 2) + (p & 3)) * 16 + ((p >> 2) & 15);
}

// ---------------- fused init: dst histogram + graph bounds + prepw ----------------
// blk < NBLKA           : per-chunk dst histogram (plain stores, no global atomics)
// blk == NBLKA          : gstart binary search
// blk == NBLKA+1        : tickets + col zero-pad + permuted bias tables
// blk >= NBLKA+2 (24)   : bf16 weight fragments (Wb1 logical k-order, Wb2/3 phi order)

__global__ __launch_bounds__(256) void k_init(const int* __restrict__ dst,
                                              int* __restrict__ hist,
                                              const int* __restrict__ batch,
                                              int* __restrict__ gstart,
                                              int* __restrict__ ticket,
                                              int* __restrict__ pticket,
                                              int* __restrict__ col,
                                              const float* __restrict__ b1,
                                              const float* __restrict__ b2,
                                              const float* __restrict__ b3,
                                              float* __restrict__ bp,
                                              const float* __restrict__ W1,
                                              const float* __restrict__ W2,
                                              const float* __restrict__ W3,
                                              unsigned short* __restrict__ O1,
                                              unsigned short* __restrict__ O2,
                                              unsigned short* __restrict__ O3) {
    __shared__ int lh[NB];
    int blk = blockIdx.x;
    int t = threadIdx.x;
    if (blk < NBLKA) {
        for (int i = t; i < NB; i += 256) lh[i] = 0;
        __syncthreads();
        int e0 = blk * EPB;
        int e1 = min(e0 + EPB, NE);
        for (int e = e0 + t; e < e1; e += 256) atomicAdd(&lh[dst[e] >> 8], 1);
        __syncthreads();
        for (int i = t; i < NB; i += 256) hist[blk * NB + i] = lh[i];
    } else if (blk == NBLKA) {
        int g = t;
        if (g > NG) return;
        int lo = 0, hi = NN;
        while (lo < hi) {
            int mid = (lo + hi) >> 1;
            if (batch[mid] < g) lo = mid + 1; else hi = mid;
        }
        gstart[g] = lo;
    } else if (blk == NBLKA + 1) {
        if (t == 0) *ticket = 0;
        if (t >= 8 && t < 16) col[NE + (t - 8)] = 0;  // pad: unclamped tail reads
        if (t < 128) {
            int c = phi(t);
            bp[t] = b1[c];
            bp[128 + t] = b2[c];
            bp[256 + t] = b3[c];
        } else {
            pticket[t - 128] = 0;  // NG == 128 per-graph pool tickets
        }
    } else {
        int bb = blk - (NBLKA + 2);
        const float* W = (bb >= 16) ? W3 : (bb >= 8) ? W2 : W1;
        unsigned short* O = (bb >= 16) ? O3 : (bb >= 8) ? O2 : O1;
        bool logical = (bb < 8);
        int idx = (bb & 7) * 256 + t;
        int l = idx & 63;
        int s = (idx >> 6) & 3;
        int tt = idx >> 8;
        int k0 = s * 32 + (l >> 4) * 8;
        int c = tt * 16 + (l & 15);
        unsigned short o[8];
#pragma unroll
        for (int j = 0; j < 8; j++) {
            int kk = logical ? (k0 + j) : phi(k0 + j);
            o[j] = f2bf(W[kk * DF + c]);
        }
        *(short8*)&O[idx * 8] = *(short8*)o;
    }
}

// ---------------- merged hscan + bscan (last-block ticket) ----------------

__global__ __launch_bounds__(512) void k_scan(int* __restrict__ hist,
                                              int* __restrict__ bhist,
                                              int* __restrict__ bbase,
                                              int* __restrict__ ticket) {
    __shared__ int sh[512];
    __shared__ int amLast;
    int b = blockIdx.x, t = threadIdx.x;
    int v = (t < NBLKA) ? hist[t * NB + b] : 0;
    sh[t] = v;
    __syncthreads();
    for (int off = 1; off < 512; off <<= 1) {
        int a = (t >= off) ? sh[t - off] : 0;
        __syncthreads();
        sh[t] += a;
        __syncthreads();
    }
    if (t < NBLKA) hist[t * NB + b] = sh[t] - v;
    if (t == 511) atomicExch(&bhist[b], sh[511]);
    __syncthreads();
    if (t == 0) {
        __threadfence();
        amLast = (atomicAdd(ticket, 1) == NB - 1) ? 1 : 0;
    }
    __syncthreads();
    if (amLast) {
        int v2 = (t < NB) ? atomicAdd(&bhist[t], 0) : 0;
        __syncthreads();
        sh[t] = v2;
        __syncthreads();
        for (int off = 1; off < 512; off <<= 1) {
            int a = (t >= off) ? sh[t - off] : 0;
            __syncthreads();
            sh[t] += a;
            __syncthreads();
        }
        if (t < NB) bbase[t] = sh[t] - v2;
        if (t == NB - 1) bbase[NB] = sh[t];
    }
}

// scatter only. ebuf packed: (src << 8) | (dst & 255)
__global__ __launch_bounds__(256) void k_pairs(const int* __restrict__ src,
                                               const int* __restrict__ dst,
                                               const int* __restrict__ hist,
                                               const int* __restrict__ bbase,
                                               int* __restrict__ ebuf) {
    __shared__ int lh[NB];
    __shared__ int lbase[NB];
    int t = threadIdx.x;
    for (int i = t; i < NB; i += 256) {
        lh[i] = 0;
        lbase[i] = bbase[i] + hist[blockIdx.x * NB + i];
    }
    __syncthreads();
    int e0 = blockIdx.x * EPB;
    int e1 = min(e0 + EPB, NE);
    for (int e = e0 + t; e < e1; e += 256) {
        int s = src[e], d = dst[e];
        int bk = d >> 8;
        int off = atomicAdd(&lh[bk], 1);
        ebuf[lbase[bk] + off] = (s << 8) | (d & 255);
    }
}

// col stores BYTE offsets (src*DF) for gather fp8 table (128 B rows)
__global__ __launch_bounds__(256) void k_build(const int* __restrict__ ebuf,
                                               const int* __restrict__ bbase,
                                               int* __restrict__ rowptr,
                                               float* __restrict__ dinv,
                                               int* __restrict__ col) {
    __shared__ int deg[256];
    __shared__ int lst[256];
    int b = blockIdx.x, t = threadIdx.x;
    int node = (b << 8) + t;
    deg[t] = 0;
    __syncthreads();
    int e0 = bbase[b], e1 = bbase[b + 1];
    for (int e = e0 + t; e < e1; e += 256) atomicAdd(&deg[ebuf[e] & 255], 1);
    __syncthreads();
    int v = deg[t];
    lst[t] = v;
    __syncthreads();
    for (int off = 1; off < 256; off <<= 1) {
        int a = (t >= off) ? lst[t - off] : 0;
        __syncthreads();
        lst[t] += a;
        __syncthreads();
    }
    int mystart = e0 + lst[t] - v;
    if (node < NN) {
        rowptr[node] = mystart;
        dinv[node] = rsqrtf((float)(v + 1));  // +1 self-loop
    }
    if (b == NB - 1 && t == 255) rowptr[NN] = e1;
    lst[t] = mystart;
    __syncthreads();
    for (int e = e0 + t; e < e1; e += 256) {
        int pk = ebuf[e];
        int p = atomicAdd(&lst[pk & 255], 1);
        col[p] = (pk >> 8) * DF;
    }
}

// ---------------- per-layer compute ----------------

__device__ __forceinline__ void gemm_core(const short8* af,
                                          const unsigned short* __restrict__ Wb,
                                          const float* __restrict__ dinv,
                                          int lane, int lm, int orow,
                                          unsigned char* __restrict__ fs8) {
    float dv[4];
#pragma unroll
    for (int j = 0; j < 4; j++) dv[j] = (orow + j < NN) ? dinv[orow + j] : 0.f;

    float res[4][8];
#pragma unroll
    for (int tt = 0; tt < 8; tt++) {
        floatx4 acc = {0.f, 0.f, 0.f, 0.f};
        const unsigned short* wp = Wb + ((size_t)(tt * 4) * 64 + lane) * 8;
        acc = __builtin_amdgcn_mfma_f32_16x16x32_bf16(af[0], *(const short8*)(wp), acc, 0, 0, 0);
        acc = __builtin_amdgcn_mfma_f32_16x16x32_bf16(af[1], *(const short8*)(wp + 512), acc, 0, 0, 0);
        acc = __builtin_amdgcn_mfma_f32_16x16x32_bf16(af[2], *(const short8*)(wp + 1024), acc, 0, 0, 0);
        acc = __builtin_amdgcn_mfma_f32_16x16x32_bf16(af[3], *(const short8*)(wp + 1536), acc, 0, 0, 0);
#pragma unroll
        for (int j = 0; j < 4; j++) res[j][tt] = acc[j] * dv[j];
    }

#pragma unroll
    for (int g = 0; g < 2; g++) {
#pragma unroll
        for (int j = 0; j < 4; j++) {
            int r = orow + j;
            if (r >= NN) continue;
            unsigned int w8 = __builtin_amdgcn_cvt_pk_fp8_f32(res[j][g * 4 + 0], res[j][g * 4 + 1], 0, false);
            w8 = __builtin_amdgcn_cvt_pk_fp8_f32(res[j][g * 4 + 2], res[j][g * 4 + 3], w8, true);
            *(unsigned int*)&fs8[(size_t)r * DF + g * 64 + lm * 4] = w8;
        }
    }
}

__global__ __launch_bounds__(256) void k_gemm1(const float* __restrict__ X,
                                               const unsigned short* __restrict__ Wb,
                                               const float* __restrict__ dinv,
                                               unsigned char* __restrict__ fs8) {
    int t = threadIdx.x;
    int wave = t >> 6, l = t & 63;
    int r0 = blockIdx.x * 64 + wave * 16;
    int lm = l & 15, q = l >> 4;

    int arow = r0 + lm;
    if (arow >= NN) arow = NN - 1;
    const float* xrow = X + (size_t)arow * DF + q * 8;
    short8 af[4];
#pragma unroll
    for (int s = 0; s < 4; s++) {
        float4 f0 = *(const float4*)(xrow + s * 32);
        float4 f1 = *(const float4*)(xrow + s * 32 + 4);
        unsigned short o[8] = {f2bf(f0.x), f2bf(f0.y), f2bf(f0.z), f2bf(f0.w),
                               f2bf(f1.x), f2bf(f1.y), f2bf(f1.z), f2bf(f1.w)};
        af[s] = *(short8*)o;
    }
    gemm_core(af, Wb, dinv, l, lm, r0 + q * 4, fs8);
}

__global__ __launch_bounds__(256) void k_gemm(const unsigned short* __restrict__ X,
                                              const unsigned short* __restrict__ Wb,
                                              const float* __restrict__ dinv,
                                              unsigned char* __restrict__ fs8) {
    int t = threadIdx.x;
    int wave = t >> 6, l = t & 63;
    int r0 = blockIdx.x * 64 + wave * 16;
    int lm = l & 15, q = l >> 4;

    int arow = r0 + lm;
    if (arow >= NN) arow = NN - 1;
    const unsigned short* xrow = X + (size_t)arow * DF + q * 8;
    short8 af[4];
#pragma unroll
    for (int s = 0; s < 4; s++) af[s] = *(const short8*)(xrow + s * 32);
    gemm_core(af, Wb, dinv, l, lm, r0 + q * 4, fs8);
}

// aggregation core (round-6 proven shape: 8-deep, unclamped col, predicated)
__device__ __forceinline__ void agg_node(const unsigned char* __restrict__ fsl, // fs8 + foff
                                         const int* __restrict__ colb,
                                         size_t selfoff, int e0, int e1,
                                         float dvn, const float* bias,
                                         float* o) {
    floatx2 acc0 = {0.f, 0.f}, acc1 = {0.f, 0.f}, acc2 = {0.f, 0.f}, acc3 = {0.f, 0.f};
    for (int base = e0; base < e1; base += 8) {
        const int* cp = colb + base;
        int cb[8];
#pragma unroll
        for (int k = 0; k < 8; k++) cb[k] = cp[k];
        uint2 vv[8];
#pragma unroll
        for (int k = 0; k < 8; k++) vv[k] = *(const uint2*)(fsl + cb[k]);
#pragma unroll
        for (int k = 0; k < 8; k++) {
            if (base + k < e1) {
                acc0 += __builtin_amdgcn_cvt_pk_f32_fp8(vv[k].x, false);
                acc1 += __builtin_amdgcn_cvt_pk_f32_fp8(vv[k].x, true);
                acc2 += __builtin_amdgcn_cvt_pk_f32_fp8(vv[k].y, false);
                acc3 += __builtin_amdgcn_cvt_pk_f32_fp8(vv[k].y, true);
            }
        }
    }
    uint2 sv = *(const uint2*)(fsl + selfoff);
    acc0 += __builtin_amdgcn_cvt_pk_f32_fp8(sv.x, false);
    acc1 += __builtin_amdgcn_cvt_pk_f32_fp8(sv.x, true);
    acc2 += __builtin_amdgcn_cvt_pk_f32_fp8(sv.y, false);
    acc3 += __builtin_amdgcn_cvt_pk_f32_fp8(sv.y, true);

    float a[8] = {acc0.x, acc0.y, acc1.x, acc1.y, acc2.x, acc2.y, acc3.x, acc3.y};
#pragma unroll
    for (int j = 0; j < 8; j++) o[j] = fmaxf(dvn * a[j] + bias[j], 0.f);
}

// 4 nodes per wave, natural order (degree-sort regressed: +33% FETCH).
__global__ __launch_bounds__(256) void k_agg(const unsigned char* __restrict__ fs8,
                                             const int* __restrict__ colb,
                                             const int* __restrict__ rowptr,
                                             const float* __restrict__ dinv,
                                             const float* __restrict__ bp,
                                             unsigned short* __restrict__ out) {
    int w = (int)((blockIdx.x * (size_t)blockDim.x + threadIdx.x) >> 6);
    int lane = threadIdx.x & 63;
    int sub = lane >> 4;
    int fo = lane & 15;
    int foff = fo * 8;
    int n = w * 4 + sub;

    float4 bA = *(const float4*)&bp[foff];
    float4 bB = *(const float4*)&bp[foff + 4];
    float bias[8] = {bA.x, bA.y, bA.z, bA.w, bB.x, bB.y, bB.z, bB.w};
    float dvn = dinv[n];
    int e0 = rowptr[n], e1 = rowptr[n + 1];

    float o[8];
    agg_node(fs8 + foff, colb, (size_t)n * DF, e0, e1, dvn, bias, o);

    uint4 pk;
    pk.x = (unsigned int)f2bf(o[0]) | ((unsigned int)f2bf(o[1]) << 16);
    pk.y = (unsigned int)f2bf(o[2]) | ((unsigned int)f2bf(o[3]) << 16);
    pk.z = (unsigned int)f2bf(o[4]) | ((unsigned int)f2bf(o[5]) << 16);
    pk.w = (unsigned int)f2bf(o[6]) | ((unsigned int)f2bf(o[7]) << 16);
    *(uint4*)&out[(size_t)n * DF + foff] = pk;
}

// ---------------- fused pooling + FC (single dispatch, per-graph ticket) ----------------
// Phase A (all NG*PCH blocks): chunk partial sums -> part (atomic stores).
// Last-arriving block per graph: reduce 8 partials (same c-order as the old
// k_poolfc -> bit-identical), un-permute into LDS, run the FC.

__global__ __launch_bounds__(256) void k_pool(const unsigned short* __restrict__ h,
                                              const int* __restrict__ gstart,
                                              float* __restrict__ part,
                                              int* __restrict__ pticket,
                                              const float* __restrict__ Wfc,
                                              const float* __restrict__ bfc,
                                              float* __restrict__ out) {
    __shared__ float2 red[256];
    __shared__ float pl[DF];
    __shared__ int amLast;
    int g = blockIdx.x >> 3, c = blockIdx.x & 7;
    int s = gstart[g], e = gstart[g + 1];
    int len = e - s;
    int cs = s + (int)(((long long)len * c) >> 3);
    int ce = s + (int)(((long long)len * (c + 1)) >> 3);
    int t = threadIdx.x;
    int fp = t & 63;
    int rs = t >> 6;
    float2 acc = make_float2(0.f, 0.f);
    for (int n = cs + rs; n < ce; n += 4) {
        unsigned int v = *(const unsigned int*)&h[(size_t)n * DF + fp * 2];
        acc.x += bf2f_lo(v);
        acc.y += bf2f_hi(v);
    }
    red[t] = acc;
    __syncthreads();
    if (rs == 0) {
        float2 a0 = red[fp], a1 = red[fp + 64], a2 = red[fp + 128], a3 = red[fp + 192];
        float ox = (a0.x + a1.x) + (a2.x + a3.x);
        float oy = (a0.y + a1.y) + (a2.y + a3.y);
        atomicExch(&part[blockIdx.x * DF + fp * 2], ox);       // device-visible store
        atomicExch(&part[blockIdx.x * DF + fp * 2 + 1], oy);
    }
    __syncthreads();
    if (t == 0) {
        __threadfence();
        amLast = (atomicAdd(&pticket[g], 1) == PCH - 1) ? 1 : 0;
    }
    __syncthreads();
    if (!amLast) return;

    if (t < DF) {
        float ssum = 0.f;
#pragma unroll
        for (int cc = 0; cc < PCH; cc++)
            ssum += atomicAdd(&part[(g * PCH + cc) * DF + t], 0.f);  // atomic load
        pl[phi(t)] = ssum / (float)max(len, 1);
    }
    __syncthreads();
    if (t < DOUT) {
        float a2 = bfc[t];
        for (int k = 0; k < DF; k++) a2 += pl[k] * Wfc[k * DOUT + t];
        out[g * DOUT + t] = a2;
    }
}

// ---------------- launch ----------------

extern "C" void kernel_launch(void* const* d_in, const int* in_sizes, int n_in,
                              void* d_out, int out_size, void* d_ws, size_t ws_size,
                              hipStream_t stream) {
    const float* x     = (const float*)d_in[0];
    const int*   ei    = (const int*)d_in[1];
    const int*   batch = (const int*)d_in[2];
    const float* W1 = (const float*)d_in[3];
    const float* b1 = (const float*)d_in[4];
    const float* W2 = (const float*)d_in[5];
    const float* b2 = (const float*)d_in[6];
    const float* W3 = (const float*)d_in[7];
    const float* b3 = (const float*)d_in[8];
    const float* Wfc = (const float*)d_in[9];
    const float* bfc = (const float*)d_in[10];
    float* out = (float*)d_out;

    char* p = (char*)d_ws;
    unsigned short* ob = (unsigned short*)p;  p += (size_t)NN * DF * sizeof(short);
    unsigned char*  fs8 = (unsigned char*)p;  p += (size_t)NN * DF + 256;
    unsigned short* Wb1 = (unsigned short*)p; p += 16384 * sizeof(short);
    unsigned short* Wb2 = (unsigned short*)p; p += 16384 * sizeof(short);
    unsigned short* Wb3 = (unsigned short*)p; p += 16384 * sizeof(short);
    float* dinv = (float*)p;           p += (size_t)NN * sizeof(float);
    int* rowptr = (int*)p;             p += (size_t)(NN + 4) * sizeof(int);
    int* col    = (int*)p;             p += (size_t)(NE + 8) * sizeof(int);
    int* ebuf   = (int*)p;             p += (size_t)NE * sizeof(int);
    int* bhist  = (int*)p;             p += (size_t)(NB + 4) * sizeof(int);
    int* bbase  = (int*)p;             p += (size_t)(NB + 4) * sizeof(int);
    int* hist   = (int*)p;             p += (size_t)NBLKA * NB * sizeof(int);
    int* gstart = (int*)p;             p += (size_t)(NG + 4) * sizeof(int);
    int* ticket = (int*)p;             p += 4 * sizeof(int);
    int* pticket = (int*)p;            p += (size_t)NG * sizeof(int);
    float* bp   = (float*)p;           p += 384 * sizeof(float);
    float* part = (float*)p;           p += (size_t)NG * PCH * DF * sizeof(float);

    const int* e_src = ei;
    const int* e_dst = ei + NE;

    // binning + CSR
    k_init<<<NBLKA + 26, 256, 0, stream>>>(e_dst, hist, batch, gstart, ticket, pticket,
                                           col, b1, b2, b3, bp,
                                           W1, W2, W3, Wb1, Wb2, Wb3);
    k_scan<<<NB, 512, 0, stream>>>(hist, bhist, bbase, ticket);
    k_pairs<<<NBLKA, 256, 0, stream>>>(e_src, e_dst, hist, bbase, ebuf);
    k_build<<<NB, 256, 0, stream>>>(ebuf, bbase, rowptr, dinv, col);

    int ggrid = (NN + 63) / 64;

    // layer 1 (direct f32 x), layers 2-3 (bf16 activations)
    k_gemm1<<<ggrid, 256, 0, stream>>>(x, Wb1, dinv, fs8);
    k_agg<<<NAGB, 256, 0, stream>>>(fs8, col, rowptr, dinv, bp, ob);
    k_gemm<<<ggrid, 256, 0, stream>>>(ob, Wb2, dinv, fs8);
    k_agg<<<NAGB, 256, 0, stream>>>(fs8, col, rowptr, dinv, bp + 128, ob);
    k_gemm<<<ggrid, 256, 0, stream>>>(ob, Wb3, dinv, fs8);
    k_agg<<<NAGB, 256, 0, stream>>>(fs8, col, rowptr, dinv, bp + 256, ob);

    // fused pool + fc (single dispatch)
    k_pool<<<NG * PCH, 256, 0, stream>>>(ob, gstart, part, pticket, Wfc, bfc, out);
}

// Round 9
// 329.002 us; speedup vs baseline: 1.0678x; 1.0433x over previous
//
#include <hip/hip_runtime.h>

#define NN 100000
#define NE 1600000
#define DF 128
#define DOUT 64
#define NG 128
#define NB 391      // ceil(NN/256) buckets of 256 nodes
#define EPB 8192    // edges per block in binning passes
#define NBLKA ((NE + EPB - 1) / EPB)  // 196
#define PCH 8       // pool chunks per graph
#define NAGB (NN / 16)  // agg blocks: 16 nodes per block (4 waves x 4 nodes)

typedef short short8 __attribute__((ext_vector_type(8)));
typedef float floatx4 __attribute__((ext_vector_type(4)));
typedef float floatx2 __attribute__((ext_vector_type(2)));

__device__ __forceinline__ unsigned short f2bf(float f) {
    unsigned int b = __float_as_uint(f);
    unsigned int r = (b + 0x7fffu + ((b >> 16) & 1u)) >> 16;
    return (unsigned short)r;
}
__device__ __forceinline__ float bf2f_lo(unsigned int v) { return __uint_as_float(v << 16); }
__device__ __forceinline__ float bf2f_hi(unsigned int v) { return __uint_as_float(v & 0xffff0000u); }

// physical feature index p -> logical feature c.
// p = g*64 + lm*4 + u  (g:0..1, lm:0..15, u:0..3), c = (g*4+u)*16 + lm
__device__ __forceinline__ int phi(int p) {
    return (((p >> 6) << 2) + (p & 3)) * 16 + ((p >> 2) & 15);
}

// ---------------- fused init: dst histogram + graph bounds + prepw ----------------
// blk < NBLKA           : per-chunk dst histogram (plain stores, no global atomics)
// blk == NBLKA          : gstart binary search
// blk == NBLKA+1        : ticket reset + col zero-pad + permuted bias tables
// blk >= NBLKA+2 (24)   : bf16 weight fragments. Wb1 in LOGICAL k-order (layer-1
//                         gemm reads x directly); Wb2/Wb3 in physical (phi) k-order.

__global__ __launch_bounds__(256) void k_init(const int* __restrict__ dst,
                                              int* __restrict__ hist,
                                              const int* __restrict__ batch,
                                              int* __restrict__ gstart,
                                              int* __restrict__ ticket,
                                              int* __restrict__ col,
                                              const float* __restrict__ b1,
                                              const float* __restrict__ b2,
                                              const float* __restrict__ b3,
                                              float* __restrict__ bp,
                                              const float* __restrict__ W1,
                                              const float* __restrict__ W2,
                                              const float* __restrict__ W3,
                                              unsigned short* __restrict__ O1,
                                              unsigned short* __restrict__ O2,
                                              unsigned short* __restrict__ O3) {
    __shared__ int lh[NB];
    int blk = blockIdx.x;
    int t = threadIdx.x;
    if (blk < NBLKA) {
        for (int i = t; i < NB; i += 256) lh[i] = 0;
        __syncthreads();
        int e0 = blk * EPB;
        int e1 = min(e0 + EPB, NE);
        for (int e = e0 + t; e < e1; e += 256) atomicAdd(&lh[dst[e] >> 8], 1);
        __syncthreads();
        for (int i = t; i < NB; i += 256) hist[blk * NB + i] = lh[i];
    } else if (blk == NBLKA) {
        int g = t;
        if (g > NG) return;
        int lo = 0, hi = NN;
        while (lo < hi) {
            int mid = (lo + hi) >> 1;
            if (batch[mid] < g) lo = mid + 1; else hi = mid;
        }
        gstart[g] = lo;
    } else if (blk == NBLKA + 1) {
        if (t == 0) *ticket = 0;
        if (t >= 8 && t < 16) col[NE + (t - 8)] = 0;  // pad: unclamped tail reads
        if (t < 128) {
            int c = phi(t);
            bp[t] = b1[c];
            bp[128 + t] = b2[c];
            bp[256 + t] = b3[c];
        }
    } else {
        int bb = blk - (NBLKA + 2);
        const float* W = (bb >= 16) ? W3 : (bb >= 8) ? W2 : W1;
        unsigned short* O = (bb >= 16) ? O3 : (bb >= 8) ? O2 : O1;
        bool logical = (bb < 8);
        int idx = (bb & 7) * 256 + t;
        int l = idx & 63;
        int s = (idx >> 6) & 3;
        int tt = idx >> 8;
        int k0 = s * 32 + (l >> 4) * 8;
        int c = tt * 16 + (l & 15);
        unsigned short o[8];
#pragma unroll
        for (int j = 0; j < 8; j++) {
            int kk = logical ? (k0 + j) : phi(k0 + j);
            o[j] = f2bf(W[kk * DF + c]);
        }
        *(short8*)&O[idx * 8] = *(short8*)o;
    }
}

// ---------------- merged hscan + bscan (last-block ticket) ----------------

__global__ __launch_bounds__(512) void k_scan(int* __restrict__ hist,
                                              int* __restrict__ bhist,
                                              int* __restrict__ bbase,
                                              int* __restrict__ ticket) {
    __shared__ int sh[512];
    __shared__ int amLast;
    int b = blockIdx.x, t = threadIdx.x;
    int v = (t < NBLKA) ? hist[t * NB + b] : 0;
    sh[t] = v;
    __syncthreads();
    for (int off = 1; off < 512; off <<= 1) {
        int a = (t >= off) ? sh[t - off] : 0;
        __syncthreads();
        sh[t] += a;
        __syncthreads();
    }
    if (t < NBLKA) hist[t * NB + b] = sh[t] - v;
    if (t == 511) atomicExch(&bhist[b], sh[511]);
    __syncthreads();
    if (t == 0) {
        __threadfence();
        amLast = (atomicAdd(ticket, 1) == NB - 1) ? 1 : 0;
    }
    __syncthreads();
    if (amLast) {
        int v2 = (t < NB) ? atomicAdd(&bhist[t], 0) : 0;
        __syncthreads();
        sh[t] = v2;
        __syncthreads();
        for (int off = 1; off < 512; off <<= 1) {
            int a = (t >= off) ? sh[t - off] : 0;
            __syncthreads();
            sh[t] += a;
            __syncthreads();
        }
        if (t < NB) bbase[t] = sh[t] - v2;
        if (t == NB - 1) bbase[NB] = sh[t];
    }
}

// scatter only. ebuf packed: (src << 8) | (dst & 255)
__global__ __launch_bounds__(256) void k_pairs(const int* __restrict__ src,
                                               const int* __restrict__ dst,
                                               const int* __restrict__ hist,
                                               const int* __restrict__ bbase,
                                               int* __restrict__ ebuf) {
    __shared__ int lh[NB];
    __shared__ int lbase[NB];
    int t = threadIdx.x;
    for (int i = t; i < NB; i += 256) {
        lh[i] = 0;
        lbase[i] = bbase[i] + hist[blockIdx.x * NB + i];
    }
    __syncthreads();
    int e0 = blockIdx.x * EPB;
    int e1 = min(e0 + EPB, NE);
    for (int e = e0 + t; e < e1; e += 256) {
        int s = src[e], d = dst[e];
        int bk = d >> 8;
        int off = atomicAdd(&lh[bk], 1);
        ebuf[lbase[bk] + off] = (s << 8) | (d & 255);
    }
}

// col stores BYTE offsets (src*DF) for gather fp8 table (128 B rows)
__global__ __launch_bounds__(256) void k_build(const int* __restrict__ ebuf,
                                               const int* __restrict__ bbase,
                                               int* __restrict__ rowptr,
                                               float* __restrict__ dinv,
                                               int* __restrict__ col) {
    __shared__ int deg[256];
    __shared__ int lst[256];
    int b = blockIdx.x, t = threadIdx.x;
    int node = (b << 8) + t;
    deg[t] = 0;
    __syncthreads();
    int e0 = bbase[b], e1 = bbase[b + 1];
    for (int e = e0 + t; e < e1; e += 256) atomicAdd(&deg[ebuf[e] & 255], 1);
    __syncthreads();
    int v = deg[t];
    lst[t] = v;
    __syncthreads();
    for (int off = 1; off < 256; off <<= 1) {
        int a = (t >= off) ? lst[t - off] : 0;
        __syncthreads();
        lst[t] += a;
        __syncthreads();
    }
    int mystart = e0 + lst[t] - v;
    if (node < NN) {
        rowptr[node] = mystart;
        dinv[node] = rsqrtf((float)(v + 1));  // +1 self-loop
    }
    if (b == NB - 1 && t == 255) rowptr[NN] = e1;
    lst[t] = mystart;
    __syncthreads();
    for (int e = e0 + t; e < e1; e += 256) {
        int pk = ebuf[e];
        int p = atomicAdd(&lst[pk & 255], 1);
        col[p] = (pk >> 8) * DF;
    }
}

// ---------------- per-layer compute ----------------

// shared MFMA+scale+fp8-pack core for the gemm kernels
__device__ __forceinline__ void gemm_core(const short8* af,
                                          const unsigned short* __restrict__ Wb,
                                          const float* __restrict__ dinv,
                                          int lane, int lm, int orow,
                                          unsigned char* __restrict__ fs8) {
    float dv[4];
#pragma unroll
    for (int j = 0; j < 4; j++) dv[j] = (orow + j < NN) ? dinv[orow + j] : 0.f;

    float res[4][8];
#pragma unroll
    for (int tt = 0; tt < 8; tt++) {
        floatx4 acc = {0.f, 0.f, 0.f, 0.f};
        const unsigned short* wp = Wb + ((size_t)(tt * 4) * 64 + lane) * 8;
        acc = __builtin_amdgcn_mfma_f32_16x16x32_bf16(af[0], *(const short8*)(wp), acc, 0, 0, 0);
        acc = __builtin_amdgcn_mfma_f32_16x16x32_bf16(af[1], *(const short8*)(wp + 512), acc, 0, 0, 0);
        acc = __builtin_amdgcn_mfma_f32_16x16x32_bf16(af[2], *(const short8*)(wp + 1024), acc, 0, 0, 0);
        acc = __builtin_amdgcn_mfma_f32_16x16x32_bf16(af[3], *(const short8*)(wp + 1536), acc, 0, 0, 0);
#pragma unroll
        for (int j = 0; j < 4; j++) res[j][tt] = acc[j] * dv[j];
    }

#pragma unroll
    for (int g = 0; g < 2; g++) {
#pragma unroll
        for (int j = 0; j < 4; j++) {
            int r = orow + j;
            if (r >= NN) continue;
            unsigned int w8 = __builtin_amdgcn_cvt_pk_fp8_f32(res[j][g * 4 + 0], res[j][g * 4 + 1], 0, false);
            w8 = __builtin_amdgcn_cvt_pk_fp8_f32(res[j][g * 4 + 2], res[j][g * 4 + 3], w8, true);
            *(unsigned int*)&fs8[(size_t)r * DF + g * 64 + lm * 4] = w8;
        }
    }
}

// layer-1 gemm: reads x (f32) directly, converts to bf16 in-register.
__global__ __launch_bounds__(256) void k_gemm1(const float* __restrict__ X,
                                               const unsigned short* __restrict__ Wb,
                                               const float* __restrict__ dinv,
                                               unsigned char* __restrict__ fs8) {
    int t = threadIdx.x;
    int wave = t >> 6, l = t & 63;
    int r0 = blockIdx.x * 64 + wave * 16;
    int lm = l & 15, q = l >> 4;

    int arow = r0 + lm;
    if (arow >= NN) arow = NN - 1;
    const float* xrow = X + (size_t)arow * DF + q * 8;
    short8 af[4];
#pragma unroll
    for (int s = 0; s < 4; s++) {
        float4 f0 = *(const float4*)(xrow + s * 32);
        float4 f1 = *(const float4*)(xrow + s * 32 + 4);
        unsigned short o[8] = {f2bf(f0.x), f2bf(f0.y), f2bf(f0.z), f2bf(f0.w),
                               f2bf(f1.x), f2bf(f1.y), f2bf(f1.z), f2bf(f1.w)};
        af[s] = *(short8*)o;
    }
    gemm_core(af, Wb, dinv, l, lm, r0 + q * 4, fs8);
}

// layers 2-3 gemm: reads bf16 activations (physical layout), Wb in phi k-order.
__global__ __launch_bounds__(256) void k_gemm(const unsigned short* __restrict__ X,
                                              const unsigned short* __restrict__ Wb,
                                              const float* __restrict__ dinv,
                                              unsigned char* __restrict__ fs8) {
    int t = threadIdx.x;
    int wave = t >> 6, l = t & 63;
    int r0 = blockIdx.x * 64 + wave * 16;
    int lm = l & 15, q = l >> 4;

    int arow = r0 + lm;
    if (arow >= NN) arow = NN - 1;
    const unsigned short* xrow = X + (size_t)arow * DF + q * 8;
    short8 af[4];
#pragma unroll
    for (int s = 0; s < 4; s++) af[s] = *(const short8*)(xrow + s * 32);
    gemm_core(af, Wb, dinv, l, lm, r0 + q * 4, fs8);
}

// aggregation core: unclamped col reads (col padded by 8 zeros; mid-list
// overreads hit the next node's valid entries). One base address + immediate
// offsets for the 8 col loads; accumulate stays predicated (bit-identical).
__device__ __forceinline__ void agg_node(const unsigned char* __restrict__ fsl, // fs8 + foff
                                         const int* __restrict__ colb,
                                         size_t selfoff, int e0, int e1,
                                         float dvn, const float* bias,
                                         float* o) {
    floatx2 acc0 = {0.f, 0.f}, acc1 = {0.f, 0.f}, acc2 = {0.f, 0.f}, acc3 = {0.f, 0.f};
    for (int base = e0; base < e1; base += 8) {
        const int* cp = colb + base;
        int cb[8];
#pragma unroll
        for (int k = 0; k < 8; k++) cb[k] = cp[k];
        uint2 vv[8];
#pragma unroll
        for (int k = 0; k < 8; k++) vv[k] = *(const uint2*)(fsl + cb[k]);
#pragma unroll
        for (int k = 0; k < 8; k++) {
            if (base + k < e1) {
                acc0 += __builtin_amdgcn_cvt_pk_f32_fp8(vv[k].x, false);
                acc1 += __builtin_amdgcn_cvt_pk_f32_fp8(vv[k].x, true);
                acc2 += __builtin_amdgcn_cvt_pk_f32_fp8(vv[k].y, false);
                acc3 += __builtin_amdgcn_cvt_pk_f32_fp8(vv[k].y, true);
            }
        }
    }
    // self-loop row (fp8, dinv[src] already folded in)
    uint2 sv = *(const uint2*)(fsl + selfoff);
    acc0 += __builtin_amdgcn_cvt_pk_f32_fp8(sv.x, false);
    acc1 += __builtin_amdgcn_cvt_pk_f32_fp8(sv.x, true);
    acc2 += __builtin_amdgcn_cvt_pk_f32_fp8(sv.y, false);
    acc3 += __builtin_amdgcn_cvt_pk_f32_fp8(sv.y, true);

    float a[8] = {acc0.x, acc0.y, acc1.x, acc1.y, acc2.x, acc2.y, acc3.x, acc3.y};
#pragma unroll
    for (int j = 0; j < 8; j++) o[j] = fmaxf(dvn * a[j] + bias[j], 0.f);
}

// 4 nodes per wave, each 16-lane sub owns one node. Permuted bias table (bp)
// replaces 8 runtime phi() evaluations with two aligned float4 loads.
__global__ __launch_bounds__(256) void k_agg(const unsigned char* __restrict__ fs8,
                                             const int* __restrict__ colb,
                                             const int* __restrict__ rowptr,
                                             const float* __restrict__ dinv,
                                             const float* __restrict__ bp,
                                             unsigned short* __restrict__ out) {
    int w = (int)((blockIdx.x * (size_t)blockDim.x + threadIdx.x) >> 6);
    int lane = threadIdx.x & 63;
    int sub = lane >> 4;
    int fo = lane & 15;
    int foff = fo * 8;
    int n = w * 4 + sub;

    float4 bA = *(const float4*)&bp[foff];
    float4 bB = *(const float4*)&bp[foff + 4];
    float bias[8] = {bA.x, bA.y, bA.z, bA.w, bB.x, bB.y, bB.z, bB.w};
    float dvn = dinv[n];
    int e0 = rowptr[n], e1 = rowptr[n + 1];

    float o[8];
    agg_node(fs8 + foff, colb, (size_t)n * DF, e0, e1, dvn, bias, o);

    uint4 pk;
    pk.x = (unsigned int)f2bf(o[0]) | ((unsigned int)f2bf(o[1]) << 16);
    pk.y = (unsigned int)f2bf(o[2]) | ((unsigned int)f2bf(o[3]) << 16);
    pk.z = (unsigned int)f2bf(o[4]) | ((unsigned int)f2bf(o[5]) << 16);
    pk.w = (unsigned int)f2bf(o[6]) | ((unsigned int)f2bf(o[7]) << 16);
    *(uint4*)&out[(size_t)n * DF + foff] = pk;
}

// ---------------- pooling + FC ----------------

__global__ __launch_bounds__(256) void k_poolA(const unsigned short* __restrict__ h,
                                               const int* __restrict__ gstart,
                                               float* __restrict__ part) {
    __shared__ float2 red[256];
    int g = blockIdx.x >> 3, c = blockIdx.x & 7;
    int s = gstart[g], e = gstart[g + 1];
    int len = e - s;
    int cs = s + (int)(((long long)len * c) >> 3);
    int ce = s + (int)(((long long)len * (c + 1)) >> 3);
    int t = threadIdx.x;
    int fp = t & 63;
    int rs = t >> 6;
    float2 acc = make_float2(0.f, 0.f);
    for (int n = cs + rs; n < ce; n += 4) {
        unsigned int v = *(const unsigned int*)&h[(size_t)n * DF + fp * 2];
        acc.x += bf2f_lo(v);
        acc.y += bf2f_hi(v);
    }
    red[t] = acc;
    __syncthreads();
    if (rs == 0) {
        float2 a0 = red[fp], a1 = red[fp + 64], a2 = red[fp + 128], a3 = red[fp + 192];
        float2 o;
        o.x = (a0.x + a1.x) + (a2.x + a3.x);
        o.y = (a0.y + a1.y) + (a2.y + a3.y);
        *(float2*)&part[(size_t)blockIdx.x * DF + fp * 2] = o;
    }
}

// phase B + FC fused: reduce partials -> pooled (LDS, un-permuted) -> FC
__global__ __launch_bounds__(128) void k_poolfc(const float* __restrict__ part,
                                                const int* __restrict__ gstart,
                                                const float* __restrict__ Wfc,
                                                const float* __restrict__ bfc,
                                                float* __restrict__ out) {
    __shared__ float pl[DF];
    int g = blockIdx.x;
    int f = threadIdx.x;
    float s = 0.f;
#pragma unroll
    for (int c = 0; c < PCH; c++) s += part[(size_t)(g * PCH + c) * DF + f];
    int cnt = gstart[g + 1] - gstart[g];
    pl[phi(f)] = s / (float)max(cnt, 1);
    __syncthreads();
    if (f < DOUT) {
        float acc = bfc[f];
        for (int k = 0; k < DF; k++) acc += pl[k] * Wfc[k * DOUT + f];
        out[g * DOUT + f] = acc;
    }
}

// ---------------- launch ----------------

extern "C" void kernel_launch(void* const* d_in, const int* in_sizes, int n_in,
                              void* d_out, int out_size, void* d_ws, size_t ws_size,
                              hipStream_t stream) {
    const float* x     = (const float*)d_in[0];
    const int*   ei    = (const int*)d_in[1];
    const int*   batch = (const int*)d_in[2];
    const float* W1 = (const float*)d_in[3];
    const float* b1 = (const float*)d_in[4];
    const float* W2 = (const float*)d_in[5];
    const float* b2 = (const float*)d_in[6];
    const float* W3 = (const float*)d_in[7];
    const float* b3 = (const float*)d_in[8];
    const float* Wfc = (const float*)d_in[9];
    const float* bfc = (const float*)d_in[10];
    float* out = (float*)d_out;

    char* p = (char*)d_ws;
    unsigned short* ob = (unsigned short*)p;  p += (size_t)NN * DF * sizeof(short);
    unsigned char*  fs8 = (unsigned char*)p;  p += (size_t)NN * DF + 256;
    unsigned short* Wb1 = (unsigned short*)p; p += 16384 * sizeof(short);
    unsigned short* Wb2 = (unsigned short*)p; p += 16384 * sizeof(short);
    unsigned short* Wb3 = (unsigned short*)p; p += 16384 * sizeof(short);
    float* dinv = (float*)p;           p += (size_t)NN * sizeof(float);
    int* rowptr = (int*)p;             p += (size_t)(NN + 4) * sizeof(int);
    int* col    = (int*)p;             p += (size_t)(NE + 8) * sizeof(int);
    int* ebuf   = (int*)p;             p += (size_t)NE * sizeof(int);
    int* bhist  = (int*)p;             p += (size_t)(NB + 4) * sizeof(int);
    int* bbase  = (int*)p;             p += (size_t)(NB + 4) * sizeof(int);
    int* hist   = (int*)p;             p += (size_t)NBLKA * NB * sizeof(int);
    int* gstart = (int*)p;             p += (size_t)(NG + 4) * sizeof(int);
    int* ticket = (int*)p;             p += 4 * sizeof(int);
    float* bp   = (float*)p;           p += 384 * sizeof(float);
    float* part = (float*)p;           p += (size_t)NG * PCH * DF * sizeof(float);

    const int* e_src = ei;
    const int* e_dst = ei + NE;

    // init (hist + bounds + ticket/pad/bias + 3x prepw), merged scans, scatter, CSR build
    k_init<<<NBLKA + 26, 256, 0, stream>>>(e_dst, hist, batch, gstart, ticket, col,
                                           b1, b2, b3, bp,
                                           W1, W2, W3, Wb1, Wb2, Wb3);
    k_scan<<<NB, 512, 0, stream>>>(hist, bhist, bbase, ticket);
    k_pairs<<<NBLKA, 256, 0, stream>>>(e_src, e_dst, hist, bbase, ebuf);
    k_build<<<NB, 256, 0, stream>>>(ebuf, bbase, rowptr, dinv, col);

    int ggrid = (NN + 63) / 64;

    // layer 1 (direct f32 x), layers 2-3 (bf16 activations)
    k_gemm1<<<ggrid, 256, 0, stream>>>(x, Wb1, dinv, fs8);
    k_agg<<<NAGB, 256, 0, stream>>>(fs8, col, rowptr, dinv, bp, ob);
    k_gemm<<<ggrid, 256, 0, stream>>>(ob, Wb2, dinv, fs8);
    k_agg<<<NAGB, 256, 0, stream>>>(fs8, col, rowptr, dinv, bp + 128, ob);
    k_gemm<<<ggrid, 256, 0, stream>>>(ob, Wb3, dinv, fs8);
    k_agg<<<NAGB, 256, 0, stream>>>(fs8, col, rowptr, dinv, bp + 256, ob);

    // pool + fc
    k_poolA<<<NG * PCH, 256, 0, stream>>>(ob, gstart, part);
    k_poolfc<<<NG, 128, 0, stream>>>(part, gstart, Wfc, bfc, out);
}